// Round 1
// baseline (842.126 us; speedup 1.0000x reference)
//
#include <hip/hip_runtime.h>
#include <cmath>

namespace {
constexpr int TT = 100;
constexpr int B = 512;
constexpr int NIN = 512;
constexpr int NOUT = 512;
constexpr int NEURONS = B * NOUT;  // 262144

// Constants computed in double (as Python does), then cast to f32 at use sites.
constexpr double D_I0 = 1e-3;
constexpr double D_KAPPA = (0.75 + 0.66) / 2.0;  // 0.705
constexpr double D_UT = 25.0e-3;
constexpr float F_I0 = (float)D_I0;
constexpr float F_TAU_AMPA = (float)(2e-3 * D_UT / (D_KAPPA * 20.0 * D_I0));
constexpr float F_TAU_GABA = (float)(2e-3 * D_UT / (D_KAPPA * 5.0 * D_I0));
constexpr float F_TAU_SOMA = (float)(2e-3 * D_UT / (D_KAPPA * 5.0 * D_I0));
constexpr float F_TAU_AHP  = (float)(4e-3 * D_UT / (D_KAPPA * 2.0 * D_I0));
constexpr float F_DPI_TAU  = (float)(5.0 * D_I0);
constexpr float F_RESET    = (float)(1.2 * D_I0);
constexpr float F_VR       = (float)(5.0 * D_I0 + D_I0);   // 6e-3
constexpr float F_TH       = (float)(2000.0 * D_I0);       // 2.0
constexpr float F_PFB_TH   = (float)(1000.0 * D_I0);       // 1.0
constexpr float F_ALPHA    = 4.0f;
constexpr float F_AMPA_GAIN = (float)(4.0 * 100.0 * D_I0); // 0.4
constexpr float F_GABA_GAIN = (float)(4.0 * 100.0 * D_I0); // 0.4
constexpr float F_AHP_GAIN  = (float)(4.0 * 2.0 * D_I0);   // 8e-3
constexpr float F_AHP_JUMP  = (float)(4.0 * D_I0);         // 4e-3
constexpr float F_PFB_NORM  = (float)(20.0 * D_I0);        // 0.02
constexpr float F_PFB_GAIN  = (float)(100.0 * D_I0);       // 0.1
constexpr float F_ALPHA_DPI = (float)(4.0 * (5.0 * D_I0)); // 0.02 (ALPHA*DPI_TAU folded in python)
constexpr float F_DT = 1e-3f;
constexpr float F_INIT_MEM = (float)(1.1 * D_I0);
}  // namespace

// C[M,512] = A[M,512] @ rint(B[512,512]); M = tc*512, grid (M/64, 8), 256 thr.
// 64x64 tile, BK=16, 4x4 micro-tile per thread, fp32.
__global__ __launch_bounds__(256) void gemm_roundB(
    const float* __restrict__ A, const float* __restrict__ Bw,
    float* __restrict__ C) {
  __shared__ float As[16][68];  // [k][m], +4 pad keeps 16B row alignment
  __shared__ float Bs[16][64];  // [k][n]
  const int tid = threadIdx.x;
  const int bm = blockIdx.x;
  const int bn = blockIdx.y;
  const int tx = tid & 15;   // output col group
  const int ty = tid >> 4;   // output row group
  const int arow = tid >> 2;         // 0..63
  const int acol = (tid & 3) << 2;   // 0,4,8,12
  const int brow = tid >> 4;         // 0..15
  const int bcol = (tid & 15) << 2;  // 0..60
  const float* Ab = A + (size_t)(bm * 64) * NIN;
  const float* Bb = Bw + bn * 64;
  float acc[4][4] = {};
  for (int k0 = 0; k0 < NIN; k0 += 16) {
    const float4 av = *(const float4*)(Ab + (size_t)arow * NIN + k0 + acol);
    const float4 bv = *(const float4*)(Bb + (size_t)(k0 + brow) * NOUT + bcol);
    __syncthreads();  // previous tile's reads complete
    As[acol + 0][arow] = av.x;
    As[acol + 1][arow] = av.y;
    As[acol + 2][arow] = av.z;
    As[acol + 3][arow] = av.w;
    float4 br;
    br.x = rintf(bv.x); br.y = rintf(bv.y); br.z = rintf(bv.z); br.w = rintf(bv.w);
    *(float4*)&Bs[brow][bcol] = br;
    __syncthreads();
#pragma unroll
    for (int k = 0; k < 16; ++k) {
      const float4 a4 = *(const float4*)&As[k][ty << 2];
      const float4 b4 = *(const float4*)&Bs[k][tx << 2];
      const float a[4] = {a4.x, a4.y, a4.z, a4.w};
      const float b[4] = {b4.x, b4.y, b4.z, b4.w};
#pragma unroll
      for (int i = 0; i < 4; ++i)
#pragma unroll
        for (int j = 0; j < 4; ++j)
          acc[i][j] += a[i] * b[j];
    }
  }
  float* Cb = C + (size_t)(bm * 64 + (ty << 2)) * NOUT + bn * 64 + (tx << 2);
#pragma unroll
  for (int i = 0; i < 4; ++i) {
    const float4 v = make_float4(acc[i][0], acc[i][1], acc[i][2], acc[i][3]);
    *(float4*)(Cb + (size_t)i * NOUT) = v;
  }
}

// One thread per neuron; scans tc timesteps with state in registers.
// Matches the JAX step() op-for-op in fp32 (incl. inf-division when ahp==0).
__global__ __launch_bounds__(256) void neuron_scan(
    const float* __restrict__ inca, const float* __restrict__ incg,
    float* __restrict__ Sout, float* __restrict__ state,
    int tc, int first) {
  const int idx = blockIdx.x * 256 + threadIdx.x;
  float mem, ampa, gaba, ahp, refr;
  if (first) {
    mem = F_INIT_MEM; ampa = F_I0; gaba = F_I0; ahp = 0.0f; refr = 0.0f;
  } else {
    mem  = state[idx];
    ampa = state[NEURONS + idx];
    gaba = state[2 * NEURONS + idx];
    ahp  = state[3 * NEURONS + idx];
    refr = state[4 * NEURONS + idx];
  }
  for (int t = 0; t < tc; ++t) {
    const float xa = F_AMPA_GAIN * inca[(size_t)t * NEURONS + idx];
    const float xg = F_GABA_GAIN * incg[(size_t)t * NEURONS + idx];
    const float pfb = F_PFB_GAIN / (1.0f + expf(-(mem - F_PFB_TH) / F_PFB_NORM));
    // ahp==0 -> F_AHP_GAIN/0 = +inf -> dahp = -0.0f (matches jnp semantics)
    const float dahp = (-F_AHP_GAIN - ahp) / (F_TAU_AHP * (1.0f + F_AHP_GAIN / ahp));
    const float Iin = fmaxf(ampa - gaba + F_I0, F_I0);
    const float Isum = F_VR + ahp - pfb;
    const float dmem = (F_ALPHA * (Iin - Isum) - Isum * mem / F_DPI_TAU)
                     / (F_TAU_SOMA * (1.0f + F_ALPHA_DPI / mem));
    const float dampa = (F_I0 - ampa) / F_TAU_AMPA;  // pre-injection
    ampa = ampa + xa;
    const float dgaba = (F_I0 - gaba) / F_TAU_GABA;  // pre-injection
    gaba = gaba + xg;
    refr = refr - (refr > 0.0f ? 1.0f : 0.0f);
    mem = mem + F_DT * dmem * (refr <= 0.0f ? 1.0f : 0.0f);
    ahp = ahp + F_DT * dahp;
    ampa = ampa + F_DT * dampa;
    gaba = gaba + F_DT * dgaba;
    const float S = (mem - F_TH) > 0.0f ? 1.0f : 0.0f;
    refr = refr + floorf(S * 5.0f);
    ahp = ahp + F_AHP_JUMP * S;
    mem = F_RESET * S + mem * (1.0f - S);
    mem = fmaxf(mem, F_I0);
    Sout[(size_t)t * NEURONS + idx] = S;
  }
  state[idx] = mem;
  state[NEURONS + idx] = ampa;
  state[2 * NEURONS + idx] = gaba;
  state[3 * NEURONS + idx] = ahp;
  state[4 * NEURONS + idx] = refr;
}

extern "C" void kernel_launch(void* const* d_in, const int* in_sizes, int n_in,
                              void* d_out, int out_size, void* d_ws, size_t ws_size,
                              hipStream_t stream) {
  const float* XA = (const float*)d_in[0];
  const float* XG = (const float*)d_in[1];
  const float* WA = (const float*)d_in[2];
  const float* WG = (const float*)d_in[3];
  float* S = (float*)d_out;
  float* ws = (float*)d_ws;

  // Chunk size over timesteps: need ws for 2 INC buffers [tc*B*NOUT] + 5 state arrays.
  int tc = 1;
  const int cands[5] = {20, 10, 5, 2, 1};
  for (int i = 0; i < 5; ++i) {
    const size_t need = ((size_t)2 * cands[i] * NEURONS + (size_t)5 * NEURONS) * sizeof(float);
    if (need <= ws_size) { tc = cands[i]; break; }
  }
  const size_t incElems = (size_t)tc * NEURONS;
  float* INCa = ws;
  float* INCg = ws + incElems;
  float* state = ws + 2 * incElems;

  const dim3 gg((unsigned)(tc * B / 64), NOUT / 64);
  const int nch = TT / tc;
  for (int c = 0; c < nch; ++c) {
    const size_t inOff = (size_t)c * tc * B * NIN;
    gemm_roundB<<<gg, 256, 0, stream>>>(XA + inOff, WA, INCa);
    gemm_roundB<<<gg, 256, 0, stream>>>(XG + inOff, WG, INCg);
    neuron_scan<<<NEURONS / 256, 256, 0, stream>>>(
        INCa, INCg, S + (size_t)c * tc * NEURONS, state, tc, c == 0 ? 1 : 0);
  }
}